// Round 14
// baseline (358.753 us; speedup 1.0000x reference)
//
#include <hip/hip_runtime.h>
#include <hip/hip_fp16.h>

// tensor  [B=512, T=64, N=512] f32 ; W_shared[R=64, N=512, R=64] f32
// W_last  [C=100, R=64, M=64, R=64] f32 ; out [C=100, B=512] f32
//
// v_b (len 64): v <- v @ M_b(t),  M_b(t)[i,k] = sum_j x[b,t,j] W_shared[i,j,k]
// out[c,b] = sum_i v_b[i] * u[c,i],  u[c,i] = sum_{m,k} W_last[c,i,m,k]
//
// Round 14: r13 + GEMM phase-skew retry with __launch_bounds__(512,2)
// (r7's regression hypothesized = VGPR cap 128 -> scratch spills; skew needs
// ~224 live regs; 2 waves/EU allows 256). Reads one phase ahead of each MFMA;
// counted vmcnt with >=1-phase lead; standard XCD swizzle; NT C stores.
// Scan = r13's barrier-free transposed scan (bik[b,t][k*64+i]).

typedef _Float16 f16;
typedef __attribute__((ext_vector_type(8))) _Float16 f16x8;
typedef __attribute__((ext_vector_type(2))) _Float16 f16x2;
typedef __attribute__((ext_vector_type(4))) float f32x4;

#define GLDS16(g, l)                                                      \
    __builtin_amdgcn_global_load_lds(                                     \
        (const __attribute__((address_space(1))) void*)(g),               \
        (__attribute__((address_space(3))) void*)(l), 16, 0, 0)

#define BARRIER() asm volatile("s_barrier" ::: "memory")
#define VMCNT(n) asm volatile("s_waitcnt vmcnt(" #n ")" ::: "memory")
#define WAVE_LDS_FENCE()                                                  \
    do {                                                                  \
        asm volatile("s_waitcnt lgkmcnt(0)" ::: "memory");                \
        __builtin_amdgcn_sched_barrier(0);                                \
    } while (0)

// ---------------- standalone usum (fallback paths) ----------------------------
__global__ __launch_bounds__(256) void k_usum(const float* __restrict__ Wl,
                                              float* __restrict__ u) {
    int ci = blockIdx.x;  // c*64 + i
    const float4* p = (const float4*)(Wl + (size_t)ci * 4096);
    int tid = threadIdx.x;
    float s = 0.f;
#pragma unroll
    for (int q = 0; q < 4; ++q) {
        float4 v = p[tid + 256 * q];
        s += v.x + v.y + v.z + v.w;
    }
    __shared__ float red[256];
    red[tid] = s;
    __syncthreads();
    if (tid < 128) red[tid] += red[tid + 128];
    __syncthreads();
    if (tid < 64) {
        float x = red[tid] + red[tid + 64];
#pragma unroll
        for (int off = 32; off > 0; off >>= 1) x += __shfl_down(x, off, 64);
        if (tid == 0) u[ci] = x;
    }
}

// ------- fused prep: cvtA (blocks 0..8191), cvtW (8192..12287), usum (rest) ---
// cvtW writes Bt in TRANSPOSED row order: Bt[k*64+i][j] = W[i,j,k].
__global__ __launch_bounds__(256) void k_prep(const float* __restrict__ tensor,
                                              const float* __restrict__ Wsh,
                                              const float* __restrict__ Wl,
                                              f16* __restrict__ Af16,
                                              f16* __restrict__ Btw,
                                              float* __restrict__ u) {
    __shared__ float red[256];
    int blk = blockIdx.x;
    int tid = threadIdx.x;
    if (blk < 8192) {
        int idx = blk * 256 + tid;
        const float4* p = (const float4*)tensor + (size_t)idx * 2;
        float4 v0 = p[0], v1 = p[1];
        f16x8 h;
        h[0] = (f16)v0.x; h[1] = (f16)v0.y; h[2] = (f16)v0.z; h[3] = (f16)v0.w;
        h[4] = (f16)v1.x; h[5] = (f16)v1.y; h[6] = (f16)v1.z; h[7] = (f16)v1.w;
        *(f16x8*)(Af16 + (size_t)idx * 8) = h;
    } else if (blk < 12288) {
        int o = (blk - 8192) * 256 + tid;
        int col = o >> 8;                    // col = k*64 + i
        int j = (o & 255) << 1;
        int k = col >> 6, i = col & 63;
        const float* src = Wsh + ((size_t)i * 512 + j) * 64 + k;
        f16x2 pk;
        pk[0] = (f16)src[0];
        pk[1] = (f16)src[64];
        *(f16x2*)(Btw + (size_t)col * 512 + j) = pk;
    } else {
        int ci = blk - 12288;
        const float4* p = (const float4*)(Wl + (size_t)ci * 4096);
        float s = 0.f;
#pragma unroll
        for (int q = 0; q < 4; ++q) {
            float4 v = p[tid + 256 * q];
            s += v.x + v.y + v.z + v.w;
        }
        red[tid] = s;
        __syncthreads();
        if (tid < 128) red[tid] += red[tid + 128];
        __syncthreads();
        if (tid < 64) {
            float x = red[tid] + red[tid + 64];
#pragma unroll
            for (int off = 32; off > 0; off >>= 1) x += __shfl_down(x, off, 64);
            if (tid == 0) u[ci] = x;
        }
    }
}

// =============== 256x256 MFMA GEMM, phase-skewed reads, 256-VGPR budget =======
// LDS (dynamic 128 KB): buf q in {0,1} at q*65536; slots within buf:
//   A0 +0, A1 +16384, B0 +32768, B1 +49152   (each 128 rows x 64 f16 = 16 KB)
// Swizzle invariant: LDS[(r<<7) + s*16] holds global 16B-slot (s ^ (r&7)).
//
// Steady kt (phases end with BARRIER; MFMA operands were read pre-barrier):
//  P0: RD b1@kt       ; STAGE A0,B0@kt+1 ; MFMA q00(a0,b0) ; VMCNT(4) [A1@kt]
//  P1: RD a1@kt       ;                    MFMA q01(a0,b1)
//  P2:                  STAGE B1,A1@kt+1 ; MFMA q10(a1,b0) ; VMCNT(4) [A0,B0@kt+1]
//  P3: RD a0,b0@kt+1  ;                    MFMA q11(a1,b1) ; VMCNT(2) [B1@kt+1]
// Per-wave vmcnt queue verified; every cross-wave DMA->ds_read crossing is
// vmcnt-before-barrier protected; every slot overwrite >=2 barriers after its
// last reader's lgkm-complete use.

#define STAGE_A(qq, ha, ktv) do {                                             \
    _Pragma("unroll") for (int u_ = 0; u_ < 2; ++u_) {                        \
        int idx_ = (wid * 2 + u_) * 64 + lane;                                \
        int r_ = idx_ >> 3;                                                   \
        int ls_ = (idx_ & 7) ^ (r_ & 7);                                      \
        const f16* g_ = A + (size_t)(m0 + (ha) * 128 + r_) * 512              \
                          + (ktv) * 64 + ls_ * 8;                             \
        char* l_ = smem + (qq) * 65536 + (ha) * 16384 + (wid * 2 + u_) * 1024;\
        GLDS16(g_, l_);                                                       \
    } } while (0)

#define STAGE_B(qq, hb, ktv) do {                                             \
    _Pragma("unroll") for (int u_ = 0; u_ < 2; ++u_) {                        \
        int idx_ = (wid * 2 + u_) * 64 + lane;                                \
        int r_ = idx_ >> 3;                                                   \
        int ls_ = (idx_ & 7) ^ (r_ & 7);                                      \
        const f16* g_ = Bt + (size_t)(n0 + (hb) * 128 + r_) * 512             \
                           + (ktv) * 64 + ls_ * 8;                            \
        char* l_ = smem + (qq) * 65536 + 32768 + (hb) * 16384                 \
                        + (wid * 2 + u_) * 1024;                              \
        GLDS16(g_, l_);                                                       \
    } } while (0)

#define RD_A(ha, ktv, areg) do {                                              \
    _Pragma("unroll") for (int mf_ = 0; mf_ < 4; ++mf_)                       \
    _Pragma("unroll") for (int kq_ = 0; kq_ < 2; ++kq_) {                     \
        int ra_ = wr * 64 + mf_ * 16 + (lane & 15);                           \
        int off_ = ((ra_ << 7) + kq_ * 64 + ((lane >> 4) << 4))               \
                   ^ ((ra_ & 7) << 4);                                        \
        areg[mf_][kq_] = *(const f16x8*)(smem + ((ktv) & 1) * 65536           \
                                         + (ha) * 16384 + off_);              \
    } } while (0)

#define RD_B(hb, ktv, breg) do {                                              \
    _Pragma("unroll") for (int nf_ = 0; nf_ < 2; ++nf_)                       \
    _Pragma("unroll") for (int kq_ = 0; kq_ < 2; ++kq_) {                     \
        int rb_ = wc * 32 + nf_ * 16 + (lane & 15);                           \
        int off_ = ((rb_ << 7) + kq_ * 64 + ((lane >> 4) << 4))               \
                   ^ ((rb_ & 7) << 4);                                        \
        breg[nf_][kq_] = *(const f16x8*)(smem + ((ktv) & 1) * 65536           \
                                         + 32768 + (hb) * 16384 + off_);      \
    } } while (0)

#define MFMA_Q(qa_, qb_, areg, breg) do {                                     \
    __builtin_amdgcn_s_setprio(1);                                            \
    _Pragma("unroll") for (int mf_ = 0; mf_ < 4; ++mf_)                       \
    _Pragma("unroll") for (int nf_ = 0; nf_ < 2; ++nf_)                       \
    _Pragma("unroll") for (int kq_ = 0; kq_ < 2; ++kq_)                       \
        acc[qa_][qb_][mf_][nf_] = __builtin_amdgcn_mfma_f32_16x16x32_f16(     \
            areg[mf_][kq_], breg[nf_][kq_], acc[qa_][qb_][mf_][nf_], 0, 0, 0);\
    __builtin_amdgcn_s_setprio(0);                                            \
    } while (0)

__global__ __launch_bounds__(512, 2) void k_gemm_256(const f16* __restrict__ A,
                                                     const f16* __restrict__ Bt,
                                                     __half* __restrict__ outp) {
    extern __shared__ char smem[];
    const int tid = threadIdx.x;
    const int lane = tid & 63;
    const int wid = tid >> 6;
    // XCD-aware swizzle (nwg=2048, 2048%8==0 -> bijective)
    int lin = blockIdx.x;
    int swz = (lin & 7) * 256 + (lin >> 3);
    const int n0 = (swz & 15) * 256;   // 16 n-blocks
    const int m0 = (swz >> 4) * 256;   // 128 m-blocks
    const int wr = wid >> 2, wc = wid & 3;  // 2M x 4N waves

    f32x4 acc[2][2][4][2];
#pragma unroll
    for (int xx = 0; xx < 2; ++xx)
#pragma unroll
        for (int yy = 0; yy < 2; ++yy)
#pragma unroll
            for (int zz = 0; zz < 4; ++zz)
#pragma unroll
                for (int ww = 0; ww < 2; ++ww) acc[xx][yy][zz][ww] = (f32x4)0.f;

    f16x8 a0[4][2], a1[4][2], b0[2][2], b1[2][2];

    // ---- prologue: stage kt0 fully + A0,B0@1; read a0,b0@0 ----
    STAGE_A(0, 0, 0);
    STAGE_B(0, 0, 0);
    STAGE_B(0, 1, 0);
    STAGE_A(0, 1, 0);
    STAGE_A(1, 0, 1);
    STAGE_B(1, 0, 1);
    VMCNT(8);            // A0@0, B0@0 complete
    BARRIER();
    RD_A(0, 0, a0);
    RD_B(0, 0, b0);
    VMCNT(4);            // B1@0, A1@0 complete (leaves A0@1, B0@1)
    BARRIER();

    // ---- kt = 0 (A0/B0@1 already staged in prologue) ----
    RD_B(1, 0, b1);
    MFMA_Q(0, 0, a0, b0);
    BARRIER();
    RD_A(1, 0, a1);
    MFMA_Q(0, 1, a0, b1);
    BARRIER();
    STAGE_B(1, 1, 1);
    STAGE_A(1, 1, 1);
    MFMA_Q(1, 0, a1, b0);
    VMCNT(4);            // A0@1, B0@1 complete
    BARRIER();
    RD_A(0, 1, a0);
    RD_B(0, 1, b0);
    MFMA_Q(1, 1, a1, b1);
    VMCNT(2);            // B1@1 complete
    BARRIER();

    // ---- steady kt = 1..6 ----
#pragma unroll
    for (int kt = 1; kt < 7; ++kt) {
        // P0
        RD_B(1, kt, b1);
        STAGE_A((kt + 1) & 1, 0, kt + 1);
        STAGE_B((kt + 1) & 1, 0, kt + 1);
        MFMA_Q(0, 0, a0, b0);
        VMCNT(4);        // A1@kt complete
        BARRIER();
        // P1
        RD_A(1, kt, a1);
        MFMA_Q(0, 1, a0, b1);
        BARRIER();
        // P2
        STAGE_B((kt + 1) & 1, 1, kt + 1);
        STAGE_A((kt + 1) & 1, 1, kt + 1);
        MFMA_Q(1, 0, a1, b0);
        VMCNT(4);        // A0@kt+1, B0@kt+1 complete
        BARRIER();
        // P3
        RD_A(0, kt + 1, a0);
        RD_B(0, kt + 1, b0);
        MFMA_Q(1, 1, a1, b1);
        VMCNT(2);        // B1@kt+1 complete
        BARRIER();
    }

    // ---- kt = 7 (no staging) ----
    RD_B(1, 7, b1);
    MFMA_Q(0, 0, a0, b0);
    VMCNT(0);            // A1@7 complete
    BARRIER();
    RD_A(1, 7, a1);
    MFMA_Q(0, 1, a0, b1);
    BARRIER();
    MFMA_Q(1, 0, a1, b0);
    BARRIER();
    MFMA_Q(1, 1, a1, b1);
    BARRIER();

    // epilogue: stage 256x256 fp16 C tile in LDS, non-temporal stores
    __half* Cs = (__half*)smem;
#pragma unroll
    for (int qa = 0; qa < 2; ++qa)
#pragma unroll
        for (int qb = 0; qb < 2; ++qb)
#pragma unroll
            for (int mf = 0; mf < 4; ++mf)
#pragma unroll
                for (int nf = 0; nf < 2; ++nf)
#pragma unroll
                    for (int j = 0; j < 4; ++j) {
                        int row = qa * 128 + wr * 64 + mf * 16 + ((lane >> 4) << 2) + j;
                        int col = qb * 128 + wc * 32 + nf * 16 + (lane & 15);
                        Cs[row * 256 + col] = __float2half(acc[qa][qb][mf][nf][j]);
                    }
    BARRIER();
#pragma unroll
    for (int it = 0; it < 16; ++it) {
        int idx = it * 512 + tid;
        int r = idx >> 5, seg = idx & 31;
        __builtin_nontemporal_store(
            *(const f32x4*)(Cs + r * 256 + seg * 8),
            (f32x4*)(outp + (size_t)(m0 + r) * 4096 + n0 + seg * 8));
    }
}

// --------- legacy fp32 GEMM (fallback; produces OLD i*64+k layout) ------------
#define BM 128
#define BN 64
#define BK 32
__global__ __launch_bounds__(256) void k_gemm(const float* __restrict__ A,
                                              const float* __restrict__ W,
                                              __half* __restrict__ out,
                                              int a_off, int a_stride) {
    __shared__ float As[BK * BM];
    __shared__ float Bs[BK * BN];
    int i0 = blockIdx.x;
    int m0 = blockIdx.y * BM;
    int tid = threadIdx.x;
    int tx = tid & 15, ty = tid >> 4;
    float acc[8][4];
#pragma unroll
    for (int q = 0; q < 8; ++q)
#pragma unroll
        for (int c = 0; c < 4; ++c) acc[q][c] = 0.f;
    const float* wbase = W + (size_t)i0 * 32768;
    for (int j0 = 0; j0 < 512; j0 += BK) {
        {
            int c4 = tid & 7;
            int r = tid >> 3;
#pragma unroll
            for (int p = 0; p < 4; ++p) {
                int row = r + 32 * p;
                float4 v = *(const float4*)(A + (size_t)a_off +
                                            (size_t)(m0 + row) * a_stride + j0 + 4 * c4);
                As[(4 * c4 + 0) * BM + row] = v.x;
                As[(4 * c4 + 1) * BM + row] = v.y;
                As[(4 * c4 + 2) * BM + row] = v.z;
                As[(4 * c4 + 3) * BM + row] = v.w;
            }
            const float4* src = (const float4*)(wbase + (size_t)j0 * 64);
            float4* dst = (float4*)Bs;
            dst[tid] = src[tid];
            dst[tid + 256] = src[tid + 256];
        }
        __syncthreads();
#pragma unroll
        for (int kk = 0; kk < BK; ++kk) {
            float bv[4], av[8];
#pragma unroll
            for (int c = 0; c < 4; ++c) bv[c] = Bs[kk * BN + 4 * tx + c];
#pragma unroll
            for (int q = 0; q < 8; ++q) av[q] = As[kk * BM + 8 * ty + q];
#pragma unroll
            for (int q = 0; q < 8; ++q)
#pragma unroll
                for (int c = 0; c < 4; ++c) acc[q][c] += av[q] * bv[c];
        }
        __syncthreads();
    }
#pragma unroll
    for (int q = 0; q < 8; ++q) {
        int m = m0 + 8 * ty + q;
        __half* o = out + (size_t)m * 4096 + i0 * 64 + 4 * tx;
#pragma unroll
        for (int c = 0; c < 4; ++c) o[c] = __float2half(acc[q][c]);
    }
}

// ---- barrier-free scan over TRANSPOSED bik (fast path) -----------------------
// bik[b*64+t][k*64+i]: thread k reads M_t column k as contiguous 128B.
__global__ __launch_bounds__(128) void k_scan_t(const __half* __restrict__ bik,
                                                const float* __restrict__ u,
                                                float* __restrict__ out) {
    __shared__ float vsh[2][64];
    const int tid = threadIdx.x;
    const int wid = tid >> 6;
    const int k = tid & 63;
    const int b = blockIdx.x * 2 + wid;
    float* vs = vsh[wid];
    const f16* row = (const f16*)bik + ((size_t)b * 64) * 4096 + k * 64;

    vs[k] = 1.0f;
    f16x8 A0[8], A1[8];
#pragma unroll
    for (int q = 0; q < 8; ++q) A0[q] = *(const f16x8*)(row + q * 8);
#pragma unroll
    for (int q = 0; q < 8; ++q) A1[q] = *(const f16x8*)(row + 4096 + q * 8);
    WAVE_LDS_FENCE();   // vs init visible to whole wave

#define SCAN_T_STEP(BUF, tnext) do {                                          \
    float s0 = 0.f, s1 = 0.f, s2 = 0.f, s3 = 0.f;                             \
    _Pragma("unroll") for (int q_ = 0; q_ < 8; q_ += 4) {                     \
        _Pragma("unroll") for (int e_ = 0; e_ < 8; ++e_) {                    \
            s0 += vs[(q_ + 0) * 8 + e_] * (float)BUF[q_ + 0][e_];             \
            s1 += vs[(q_ + 1) * 8 + e_] * (float)BUF[q_ + 1][e_];             \
            s2 += vs[(q_ + 2) * 8 + e_] * (float)BUF[q_ + 2][e_];             \
            s3 += vs[(q_ + 3) * 8 + e_] * (float)BUF[q_ + 3][e_];             \
        }                                                                     \
    }                                                                         \
    if ((tnext) < 64) {                                                       \
        const f16* r_ = row + (size_t)(tnext) * 4096;                         \
        _Pragma("unroll") for (int q_ = 0; q_ < 8; ++q_)                      \
            BUF[q_] = *(const f16x8*)(r_ + q_ * 8);                           \
    }                                                                         \
    vs[k] = (s0 + s1) + (s2 + s3);                                            \
    WAVE_LDS_FENCE();                                                         \
    } while (0)

    for (int t = 0; t < 64; t += 2) {
        SCAN_T_STEP(A0, t + 2);
        SCAN_T_STEP(A1, t + 3);
    }

    for (int c = k; c < 100; c += 64) {
        const float* uc = u + c * 64;
        float s = 0.f;
#pragma unroll 8
        for (int i = 0; i < 64; ++i) s += uc[i] * vs[i];
        out[c * 512 + b] = s;
    }
}

// ---------- legacy scan over OLD-layout bik (fp32 fallback path) --------------
__global__ __launch_bounds__(256) void k_scan(const __half* __restrict__ bik,
                                              const float* __restrict__ u,
                                              float* __restrict__ out) {
    __shared__ char sm[2][8192];
    __shared__ float vsh[64];
    __shared__ float part[256];
    int b = blockIdx.x;
    int tid = threadIdx.x;
    int k = tid & 63, grp = tid >> 6;
    const int lane = tid & 63;
    const int wid = tid >> 6;
    if (tid < 64) vsh[tid] = 1.0f;
    const char* base = (const char*)(bik + (size_t)b * 64 * 4096);
#pragma unroll
    for (int u_ = 0; u_ < 2; ++u_) {
        const char* g = base + (wid * 2 + u_) * 1024 + lane * 16;
        GLDS16(g, &sm[0][0] + (wid * 2 + u_) * 1024);
    }
    for (int t = 0; t < 64; ++t) {
        VMCNT(0);
        __syncthreads();
        if (t < 63) {
            const char* gb = base + (size_t)(t + 1) * 8192;
#pragma unroll
            for (int u_ = 0; u_ < 2; ++u_) {
                const char* g = gb + (wid * 2 + u_) * 1024 + lane * 16;
                GLDS16(g, &sm[(t + 1) & 1][0] + (wid * 2 + u_) * 1024);
            }
        }
        const __half* Mt = (const __half*)&sm[t & 1][0];
        float s = 0.f;
#pragma unroll
        for (int q = 0; q < 16; ++q) {
            int i = grp * 16 + q;
            s += vsh[i] * __half2float(Mt[i * 64 + k]);
        }
        part[tid] = s;
        __syncthreads();
        if (tid < 64) vsh[k] = part[k] + part[64 + k] + part[128 + k] + part[192 + k];
        __syncthreads();
    }
    if (tid < 100) {
        const float* uc = u + tid * 64;
        float s = 0.f;
#pragma unroll 8
        for (int i = 0; i < 64; ++i) s += uc[i] * vsh[i];
        out[tid * 512 + b] = s;
    }
}

// ---------------- fallback per-t update --------------------------------------
__global__ __launch_bounds__(256) void k_update(const __half* __restrict__ Mt,
                                                const float* __restrict__ vin,
                                                float* __restrict__ vout, int first) {
    int o = blockIdx.x * 256 + threadIdx.x;
    int b = o >> 6, k = o & 63;
    const __half* m = Mt + (size_t)b * 4096;
    float s = 0.f;
    if (first) {
#pragma unroll 8
        for (int i = 0; i < 64; ++i) s += __half2float(m[i * 64 + k]);
    } else {
        const float* v = vin + (size_t)b * 64;
#pragma unroll 8
        for (int i = 0; i < 64; ++i) s += v[i] * __half2float(m[i * 64 + k]);
    }
    vout[o] = s;
}

// ---------------- out[c,b] = sum_i u[c,i] * v[b,i] (fallback path) ------------
__global__ __launch_bounds__(256) void k_final(const float* __restrict__ u,
                                               const float* __restrict__ v,
                                               float* __restrict__ out) {
    int o = blockIdx.x * 256 + threadIdx.x;
    int c = o >> 9, b = o & 511;
    const float* uc = u + c * 64;
    const float* vb = v + (size_t)b * 64;
    float s = 0.f;
#pragma unroll 8
    for (int i = 0; i < 64; ++i) s += uc[i] * vb[i];
    out[o] = s;
}

extern "C" void kernel_launch(void* const* d_in, const int* in_sizes, int n_in,
                              void* d_out, int out_size, void* d_ws, size_t ws_size,
                              hipStream_t stream) {
    const float* tensor = (const float*)d_in[0];
    const float* Wsh = (const float*)d_in[1];
    const float* Wl = (const float*)d_in[2];
    float* out = (float*)d_out;
    char* ws = (char*)d_ws;

    const size_t bik_bytes = (size_t)32768 * 4096 * sizeof(__half);  // 256 MB
    const size_t fast_bytes = bik_bytes + (512u << 10) + ((size_t)16777216 * 2) + ((size_t)4096 * 512 * 2);

    if (ws_size >= fast_bytes) {
        // ---- fp16 MFMA path (transposed bik + barrier-free scan) ----
        __half* bik = (__half*)ws;
        float* u = (float*)(ws + bik_bytes);
        f16* Af16 = (f16*)(ws + bik_bytes + (512u << 10));
        f16* Btw = Af16 + (size_t)16777216;

        k_prep<<<18688, 256, 0, stream>>>(tensor, Wsh, Wl, Af16, Btw, u);
        (void)hipFuncSetAttribute((const void*)k_gemm_256,
                                  hipFuncAttributeMaxDynamicSharedMemorySize, 131072);
        k_gemm_256<<<2048, 512, 131072, stream>>>(Af16, Btw, bik);
        k_scan_t<<<256, 128, 0, stream>>>(bik, u, out);
    } else if (ws_size >= bik_bytes + (2u << 20)) {
        // ---- fp32 big path (old layout) ----
        __half* bik = (__half*)ws;
        float* u = (float*)(ws + bik_bytes);

        k_usum<<<6400, 256, 0, stream>>>(Wl, u);
        dim3 g(64, 256);
        k_gemm<<<g, 256, 0, stream>>>(tensor, Wsh, bik, 0, 512);
        k_scan<<<512, 256, 0, stream>>>(bik, u, out);
    } else {
        // ---- per-t fallback ----
        __half* bikt = (__half*)ws;
        float* u = (float*)(ws + (size_t)(4 << 20));
        float* v0 = (float*)(ws + (size_t)(4 << 20) + (64 << 10));
        float* v1 = v0 + 32768;

        k_usum<<<6400, 256, 0, stream>>>(Wl, u);
        for (int t = 0; t < 64; ++t) {
            dim3 g(64, 4);
            k_gemm<<<g, 256, 0, stream>>>(tensor, Wsh, bikt, t * 512, 32768);
            float* vin = (t & 1) ? v0 : v1;
            float* vout = (t & 1) ? v1 : v0;
            k_update<<<128, 256, 0, stream>>>(bikt, (t == 0) ? v0 : vin, vout, t == 0);
        }
        k_final<<<200, 256, 0, stream>>>(u, v1, out);
    }
}

// Round 15
// 251.029 us; speedup vs baseline: 1.4291x; 1.4291x over previous
//
#include <hip/hip_runtime.h>
#include <hip/hip_fp16.h>

// tensor  [B=512, T=64, N=512] f32 ; W_shared[R=64, N=512, R=64] f32
// W_last  [C=100, R=64, M=64, R=64] f32 ; out [C=100, B=512] f32
//
// v_b (len 64): v <- v @ M_b(t),  M_b(t)[i,k] = sum_j x[b,t,j] W_shared[i,j,k]
// out[c,b] = sum_i v_b[i] * u[c,i],  u[c,i] = sum_{m,k} W_last[c,i,m,k]
//
// Round 15 = round 13 reverted verbatim (best validated: 251.1 us).
// Bt rows ordered k*64+i (free transpose in cvtW) so the GEMM emits
// bik[b,t][k*64+i]; scan reads M_t column k as a contiguous 128B row ->
// barrier-free 1-wave-per-b scan with register prefetch.
// GEMM = round-6 schedule + NT stores (validated x4). prep = fused.

typedef _Float16 f16;
typedef __attribute__((ext_vector_type(8))) _Float16 f16x8;
typedef __attribute__((ext_vector_type(2))) _Float16 f16x2;
typedef __attribute__((ext_vector_type(4))) float f32x4;

#define GLDS16(g, l)                                                      \
    __builtin_amdgcn_global_load_lds(                                     \
        (const __attribute__((address_space(1))) void*)(g),               \
        (__attribute__((address_space(3))) void*)(l), 16, 0, 0)

#define BARRIER() asm volatile("s_barrier" ::: "memory")
#define VMCNT(n) asm volatile("s_waitcnt vmcnt(" #n ")" ::: "memory")
#define WAVE_LDS_FENCE()                                                  \
    do {                                                                  \
        asm volatile("s_waitcnt lgkmcnt(0)" ::: "memory");                \
        __builtin_amdgcn_sched_barrier(0);                                \
    } while (0)

// ---------------- standalone usum (fallback paths) ----------------------------
__global__ __launch_bounds__(256) void k_usum(const float* __restrict__ Wl,
                                              float* __restrict__ u) {
    int ci = blockIdx.x;  // c*64 + i
    const float4* p = (const float4*)(Wl + (size_t)ci * 4096);
    int tid = threadIdx.x;
    float s = 0.f;
#pragma unroll
    for (int q = 0; q < 4; ++q) {
        float4 v = p[tid + 256 * q];
        s += v.x + v.y + v.z + v.w;
    }
    __shared__ float red[256];
    red[tid] = s;
    __syncthreads();
    if (tid < 128) red[tid] += red[tid + 128];
    __syncthreads();
    if (tid < 64) {
        float x = red[tid] + red[tid + 64];
#pragma unroll
        for (int off = 32; off > 0; off >>= 1) x += __shfl_down(x, off, 64);
        if (tid == 0) u[ci] = x;
    }
}

// ------- fused prep: cvtA (blocks 0..8191), cvtW (8192..12287), usum (rest) ---
// cvtW writes Bt in TRANSPOSED row order: Bt[k*64+i][j] = W[i,j,k].
__global__ __launch_bounds__(256) void k_prep(const float* __restrict__ tensor,
                                              const float* __restrict__ Wsh,
                                              const float* __restrict__ Wl,
                                              f16* __restrict__ Af16,
                                              f16* __restrict__ Btw,
                                              float* __restrict__ u) {
    __shared__ float red[256];
    int blk = blockIdx.x;
    int tid = threadIdx.x;
    if (blk < 8192) {
        int idx = blk * 256 + tid;
        const float4* p = (const float4*)tensor + (size_t)idx * 2;
        float4 v0 = p[0], v1 = p[1];
        f16x8 h;
        h[0] = (f16)v0.x; h[1] = (f16)v0.y; h[2] = (f16)v0.z; h[3] = (f16)v0.w;
        h[4] = (f16)v1.x; h[5] = (f16)v1.y; h[6] = (f16)v1.z; h[7] = (f16)v1.w;
        *(f16x8*)(Af16 + (size_t)idx * 8) = h;
    } else if (blk < 12288) {
        int o = (blk - 8192) * 256 + tid;
        int col = o >> 8;                    // col = k*64 + i
        int j = (o & 255) << 1;
        int k = col >> 6, i = col & 63;
        const float* src = Wsh + ((size_t)i * 512 + j) * 64 + k;
        f16x2 pk;
        pk[0] = (f16)src[0];
        pk[1] = (f16)src[64];
        *(f16x2*)(Btw + (size_t)col * 512 + j) = pk;
    } else {
        int ci = blk - 12288;
        const float4* p = (const float4*)(Wl + (size_t)ci * 4096);
        float s = 0.f;
#pragma unroll
        for (int q = 0; q < 4; ++q) {
            float4 v = p[tid + 256 * q];
            s += v.x + v.y + v.z + v.w;
        }
        red[tid] = s;
        __syncthreads();
        if (tid < 128) red[tid] += red[tid + 128];
        __syncthreads();
        if (tid < 64) {
            float x = red[tid] + red[tid + 64];
#pragma unroll
            for (int off = 32; off > 0; off >>= 1) x += __shfl_down(x, off, 64);
            if (tid == 0) u[ci] = x;
        }
    }
}

// =============== 256x256 MFMA GEMM, 4-barrier/1-vmcnt K-tiles =================
// (round-6 schedule + NT stores; byte-identical to round 12/13)
#define STAGE_A(qq, ha, ktv) do {                                             \
    _Pragma("unroll") for (int u_ = 0; u_ < 2; ++u_) {                        \
        int idx_ = (wid * 2 + u_) * 64 + lane;                                \
        int r_ = idx_ >> 3;                                                   \
        int ls_ = (idx_ & 7) ^ (r_ & 7);                                      \
        const f16* g_ = A + (size_t)(m0 + (ha) * 128 + r_) * 512              \
                          + (ktv) * 64 + ls_ * 8;                             \
        char* l_ = smem + (qq) * 65536 + (ha) * 16384 + (wid * 2 + u_) * 1024;\
        GLDS16(g_, l_);                                                       \
    } } while (0)

#define STAGE_B(qq, hb, ktv) do {                                             \
    _Pragma("unroll") for (int u_ = 0; u_ < 2; ++u_) {                        \
        int idx_ = (wid * 2 + u_) * 64 + lane;                                \
        int r_ = idx_ >> 3;                                                   \
        int ls_ = (idx_ & 7) ^ (r_ & 7);                                      \
        const f16* g_ = Bt + (size_t)(n0 + (hb) * 128 + r_) * 512             \
                           + (ktv) * 64 + ls_ * 8;                            \
        char* l_ = smem + (qq) * 65536 + 32768 + (hb) * 16384                 \
                        + (wid * 2 + u_) * 1024;                              \
        GLDS16(g_, l_);                                                       \
    } } while (0)

#define RD_A(ha, ktv) do {                                                    \
    _Pragma("unroll") for (int mf_ = 0; mf_ < 4; ++mf_)                       \
    _Pragma("unroll") for (int kq_ = 0; kq_ < 2; ++kq_) {                     \
        int ra_ = wr * 64 + mf_ * 16 + (lane & 15);                           \
        int off_ = ((ra_ << 7) + kq_ * 64 + ((lane >> 4) << 4))               \
                   ^ ((ra_ & 7) << 4);                                        \
        a[mf_][kq_] = *(const f16x8*)(smem + ((ktv) & 1) * 65536              \
                                      + (ha) * 16384 + off_);                 \
    } } while (0)

#define RD_B(hb, ktv, breg) do {                                              \
    _Pragma("unroll") for (int nf_ = 0; nf_ < 2; ++nf_)                       \
    _Pragma("unroll") for (int kq_ = 0; kq_ < 2; ++kq_) {                     \
        int rb_ = wc * 32 + nf_ * 16 + (lane & 15);                           \
        int off_ = ((rb_ << 7) + kq_ * 64 + ((lane >> 4) << 4))               \
                   ^ ((rb_ & 7) << 4);                                        \
        breg[nf_][kq_] = *(const f16x8*)(smem + ((ktv) & 1) * 65536           \
                                         + 32768 + (hb) * 16384 + off_);      \
    } } while (0)

#define MFMA_Q(qa_, qb_, breg) do {                                           \
    __builtin_amdgcn_s_setprio(1);                                            \
    _Pragma("unroll") for (int mf_ = 0; mf_ < 4; ++mf_)                       \
    _Pragma("unroll") for (int nf_ = 0; nf_ < 2; ++nf_)                       \
    _Pragma("unroll") for (int kq_ = 0; kq_ < 2; ++kq_)                       \
        acc[qa_][qb_][mf_][nf_] = __builtin_amdgcn_mfma_f32_16x16x32_f16(     \
            a[mf_][kq_], breg[nf_][kq_], acc[qa_][qb_][mf_][nf_], 0, 0, 0);   \
    __builtin_amdgcn_s_setprio(0);                                            \
    } while (0)

__global__ __launch_bounds__(512) void k_gemm_256(const f16* __restrict__ A,
                                                  const f16* __restrict__ Bt,
                                                  __half* __restrict__ outp) {
    extern __shared__ char smem[];
    const int tid = threadIdx.x;
    const int lane = tid & 63;
    const int wid = tid >> 6;
    int lin = blockIdx.x;
    int swz = (lin & 7) * 256 + (lin >> 3);
    const int n0 = (swz & 15) * 256;
    const int m0 = (swz >> 4) * 256;
    const int wr = wid >> 2, wc = wid & 3;

    f32x4 acc[2][2][4][2];
#pragma unroll
    for (int x = 0; x < 2; ++x)
#pragma unroll
        for (int y = 0; y < 2; ++y)
#pragma unroll
            for (int z = 0; z < 4; ++z)
#pragma unroll
                for (int w = 0; w < 2; ++w) acc[x][y][z][w] = (f32x4)0.f;

    f16x8 a[4][2], b0[2][2], b1[2][2];

    STAGE_A(0, 0, 0);
    STAGE_B(0, 0, 0);
    STAGE_B(0, 1, 0);
    STAGE_A(0, 1, 0);
    STAGE_A(1, 0, 1);
    STAGE_B(1, 0, 1);
    STAGE_B(1, 1, 1);

    for (int kt = 0; kt < 6; ++kt) {
        VMCNT(6);
        BARRIER();
        RD_A(0, kt);
        RD_B(0, kt, b0);
        STAGE_A((kt + 1) & 1, 1, kt + 1);
        MFMA_Q(0, 0, b0);
        BARRIER();
        RD_B(1, kt, b1);
        MFMA_Q(0, 1, b1);
        BARRIER();
        RD_A(1, kt);
        STAGE_A(kt & 1, 0, kt + 2);
        STAGE_B(kt & 1, 0, kt + 2);
        MFMA_Q(1, 0, b0);
        BARRIER();
        STAGE_B(kt & 1, 1, kt + 2);
        MFMA_Q(1, 1, b1);
        BARRIER();
    }
    {   // kt = 6
        VMCNT(6);
        BARRIER();
        RD_A(0, 6);
        RD_B(0, 6, b0);
        STAGE_A(1, 1, 7);
        MFMA_Q(0, 0, b0);
        BARRIER();
        RD_B(1, 6, b1);
        MFMA_Q(0, 1, b1);
        BARRIER();
        RD_A(1, 6);
        MFMA_Q(1, 0, b0);
        BARRIER();
        MFMA_Q(1, 1, b1);
        BARRIER();
    }
    {   // kt = 7
        VMCNT(0);
        BARRIER();
        RD_A(0, 7);
        RD_B(0, 7, b0);
        MFMA_Q(0, 0, b0);
        BARRIER();
        RD_B(1, 7, b1);
        MFMA_Q(0, 1, b1);
        BARRIER();
        RD_A(1, 7);
        MFMA_Q(1, 0, b0);
        BARRIER();
        MFMA_Q(1, 1, b1);
        BARRIER();
    }

    __half* Cs = (__half*)smem;
#pragma unroll
    for (int qa = 0; qa < 2; ++qa)
#pragma unroll
        for (int qb = 0; qb < 2; ++qb)
#pragma unroll
            for (int mf = 0; mf < 4; ++mf)
#pragma unroll
                for (int nf = 0; nf < 2; ++nf)
#pragma unroll
                    for (int j = 0; j < 4; ++j) {
                        int row = qa * 128 + wr * 64 + mf * 16 + ((lane >> 4) << 2) + j;
                        int col = qb * 128 + wc * 32 + nf * 16 + (lane & 15);
                        Cs[row * 256 + col] = __float2half(acc[qa][qb][mf][nf][j]);
                    }
    BARRIER();
#pragma unroll
    for (int it = 0; it < 16; ++it) {
        int idx = it * 512 + tid;
        int r = idx >> 5, seg = idx & 31;
        __builtin_nontemporal_store(
            *(const f32x4*)(Cs + r * 256 + seg * 8),
            (f32x4*)(outp + (size_t)(m0 + r) * 4096 + n0 + seg * 8));
    }
}

// --------- legacy fp32 GEMM (fallback; produces OLD i*64+k layout) ------------
#define BM 128
#define BN 64
#define BK 32
__global__ __launch_bounds__(256) void k_gemm(const float* __restrict__ A,
                                              const float* __restrict__ W,
                                              __half* __restrict__ out,
                                              int a_off, int a_stride) {
    __shared__ float As[BK * BM];
    __shared__ float Bs[BK * BN];
    int i0 = blockIdx.x;
    int m0 = blockIdx.y * BM;
    int tid = threadIdx.x;
    int tx = tid & 15, ty = tid >> 4;
    float acc[8][4];
#pragma unroll
    for (int q = 0; q < 8; ++q)
#pragma unroll
        for (int c = 0; c < 4; ++c) acc[q][c] = 0.f;
    const float* wbase = W + (size_t)i0 * 32768;
    for (int j0 = 0; j0 < 512; j0 += BK) {
        {
            int c4 = tid & 7;
            int r = tid >> 3;
#pragma unroll
            for (int p = 0; p < 4; ++p) {
                int row = r + 32 * p;
                float4 v = *(const float4*)(A + (size_t)a_off +
                                            (size_t)(m0 + row) * a_stride + j0 + 4 * c4);
                As[(4 * c4 + 0) * BM + row] = v.x;
                As[(4 * c4 + 1) * BM + row] = v.y;
                As[(4 * c4 + 2) * BM + row] = v.z;
                As[(4 * c4 + 3) * BM + row] = v.w;
            }
            const float4* src = (const float4*)(wbase + (size_t)j0 * 64);
            float4* dst = (float4*)Bs;
            dst[tid] = src[tid];
            dst[tid + 256] = src[tid + 256];
        }
        __syncthreads();
#pragma unroll
        for (int kk = 0; kk < BK; ++kk) {
            float bv[4], av[8];
#pragma unroll
            for (int c = 0; c < 4; ++c) bv[c] = Bs[kk * BN + 4 * tx + c];
#pragma unroll
            for (int q = 0; q < 8; ++q) av[q] = As[kk * BM + 8 * ty + q];
#pragma unroll
            for (int q = 0; q < 8; ++q)
#pragma unroll
                for (int c = 0; c < 4; ++c) acc[q][c] += av[q] * bv[c];
        }
        __syncthreads();
    }
#pragma unroll
    for (int q = 0; q < 8; ++q) {
        int m = m0 + 8 * ty + q;
        __half* o = out + (size_t)m * 4096 + i0 * 64 + 4 * tx;
#pragma unroll
        for (int c = 0; c < 4; ++c) o[c] = __float2half(acc[q][c]);
    }
}

// ---- barrier-free scan over TRANSPOSED bik (fast path) -----------------------
// bik[b*64+t][k*64+i]: thread k reads M_t column k as contiguous 128B.
// 1 wave per b (lockstep; DS ops in-order per wave; cross-lane visibility via
// lgkmcnt(0)+sched_barrier). v in per-wave LDS, broadcast reads. 2-deep
// register prefetch (named bufs A0/A1). 4-way split accumulator.
__global__ __launch_bounds__(128) void k_scan_t(const __half* __restrict__ bik,
                                                const float* __restrict__ u,
                                                float* __restrict__ out) {
    __shared__ float vsh[2][64];
    const int tid = threadIdx.x;
    const int wid = tid >> 6;
    const int k = tid & 63;
    const int b = blockIdx.x * 2 + wid;
    float* vs = vsh[wid];
    const f16* row = (const f16*)bik + ((size_t)b * 64) * 4096 + k * 64;

    vs[k] = 1.0f;
    f16x8 A0[8], A1[8];
#pragma unroll
    for (int q = 0; q < 8; ++q) A0[q] = *(const f16x8*)(row + q * 8);
#pragma unroll
    for (int q = 0; q < 8; ++q) A1[q] = *(const f16x8*)(row + 4096 + q * 8);
    WAVE_LDS_FENCE();   // vs init visible to whole wave

#define SCAN_T_STEP(BUF, tnext) do {                                          \
    float s0 = 0.f, s1 = 0.f, s2 = 0.f, s3 = 0.f;                             \
    _Pragma("unroll") for (int q_ = 0; q_ < 8; q_ += 4) {                     \
        _Pragma("unroll") for (int e_ = 0; e_ < 8; ++e_) {                    \
            s0 += vs[(q_ + 0) * 8 + e_] * (float)BUF[q_ + 0][e_];             \
            s1 += vs[(q_ + 1) * 8 + e_] * (float)BUF[q_ + 1][e_];             \
            s2 += vs[(q_ + 2) * 8 + e_] * (float)BUF[q_ + 2][e_];             \
            s3 += vs[(q_ + 3) * 8 + e_] * (float)BUF[q_ + 3][e_];             \
        }                                                                     \
    }                                                                         \
    if ((tnext) < 64) {                                                       \
        const f16* r_ = row + (size_t)(tnext) * 4096;                         \
        _Pragma("unroll") for (int q_ = 0; q_ < 8; ++q_)                      \
            BUF[q_] = *(const f16x8*)(r_ + q_ * 8);                           \
    }                                                                         \
    vs[k] = (s0 + s1) + (s2 + s3);                                            \
    WAVE_LDS_FENCE();                                                         \
    } while (0)

    for (int t = 0; t < 64; t += 2) {
        SCAN_T_STEP(A0, t + 2);
        SCAN_T_STEP(A1, t + 3);
    }

    // out[c, b] = sum_i u[c,i] * v[i]   (threads k and k+64 handle c's)
    for (int c = k; c < 100; c += 64) {
        const float* uc = u + c * 64;
        float s = 0.f;
#pragma unroll 8
        for (int i = 0; i < 64; ++i) s += uc[i] * vs[i];
        out[c * 512 + b] = s;
    }
}

// ---------- legacy scan over OLD-layout bik (fp32 fallback path) --------------
__global__ __launch_bounds__(256) void k_scan(const __half* __restrict__ bik,
                                              const float* __restrict__ u,
                                              float* __restrict__ out) {
    __shared__ char sm[2][8192];
    __shared__ float vsh[64];
    __shared__ float part[256];
    int b = blockIdx.x;
    int tid = threadIdx.x;
    int k = tid & 63, grp = tid >> 6;
    const int lane = tid & 63;
    const int wid = tid >> 6;
    if (tid < 64) vsh[tid] = 1.0f;
    const char* base = (const char*)(bik + (size_t)b * 64 * 4096);
#pragma unroll
    for (int u_ = 0; u_ < 2; ++u_) {
        const char* g = base + (wid * 2 + u_) * 1024 + lane * 16;
        GLDS16(g, &sm[0][0] + (wid * 2 + u_) * 1024);
    }
    for (int t = 0; t < 64; ++t) {
        VMCNT(0);
        __syncthreads();
        if (t < 63) {
            const char* gb = base + (size_t)(t + 1) * 8192;
#pragma unroll
            for (int u_ = 0; u_ < 2; ++u_) {
                const char* g = gb + (wid * 2 + u_) * 1024 + lane * 16;
                GLDS16(g, &sm[(t + 1) & 1][0] + (wid * 2 + u_) * 1024);
            }
        }
        const __half* Mt = (const __half*)&sm[t & 1][0];
        float s = 0.f;
#pragma unroll
        for (int q = 0; q < 16; ++q) {
            int i = grp * 16 + q;
            s += vsh[i] * __half2float(Mt[i * 64 + k]);
        }
        part[tid] = s;
        __syncthreads();
        if (tid < 64) vsh[k] = part[k] + part[64 + k] + part[128 + k] + part[192 + k];
        __syncthreads();
    }
    if (tid < 100) {
        const float* uc = u + tid * 64;
        float s = 0.f;
#pragma unroll 8
        for (int i = 0; i < 64; ++i) s += uc[i] * vsh[i];
        out[tid * 512 + b] = s;
    }
}

// ---------------- fallback per-t update --------------------------------------
__global__ __launch_bounds__(256) void k_update(const __half* __restrict__ Mt,
                                                const float* __restrict__ vin,
                                                float* __restrict__ vout, int first) {
    int o = blockIdx.x * 256 + threadIdx.x;
    int b = o >> 6, k = o & 63;
    const __half* m = Mt + (size_t)b * 4096;
    float s = 0.f;
    if (first) {
#pragma unroll 8
        for (int i = 0; i < 64; ++i) s += __half2float(m[i * 64 + k]);
    } else {
        const float* v = vin + (size_t)b * 64;
#pragma unroll 8
        for (int i = 0; i < 64; ++i) s += v[i] * __half2float(m[i * 64 + k]);
    }
    vout[o] = s;
}

// ---------------- out[c,b] = sum_i u[c,i] * v[b,i] (fallback path) ------------
__global__ __launch_bounds__(256) void k_final(const float* __restrict__ u,
                                               const float* __restrict__ v,
                                               float* __restrict__ out) {
    int o = blockIdx.x * 256 + threadIdx.x;
    int c = o >> 9, b = o & 511;
    const float* uc = u + c * 64;
    const float* vb = v + (size_t)b * 64;
    float s = 0.f;
#pragma unroll 8
    for (int i = 0; i < 64; ++i) s += uc[i] * vb[i];
    out[o] = s;
}

extern "C" void kernel_launch(void* const* d_in, const int* in_sizes, int n_in,
                              void* d_out, int out_size, void* d_ws, size_t ws_size,
                              hipStream_t stream) {
    const float* tensor = (const float*)d_in[0];
    const float* Wsh = (const float*)d_in[1];
    const float* Wl = (const float*)d_in[2];
    float* out = (float*)d_out;
    char* ws = (char*)d_ws;

    const size_t bik_bytes = (size_t)32768 * 4096 * sizeof(__half);  // 256 MB
    const size_t fast_bytes = bik_bytes + (512u << 10) + ((size_t)16777216 * 2) + ((size_t)4096 * 512 * 2);

    if (ws_size >= fast_bytes) {
        // ---- fp16 MFMA path (transposed bik + barrier-free scan) ----
        __half* bik = (__half*)ws;
        float* u = (float*)(ws + bik_bytes);
        f16* Af16 = (f16*)(ws + bik_bytes + (512u << 10));
        f16* Btw = Af16 + (size_t)16777216;

        k_prep<<<18688, 256, 0, stream>>>(tensor, Wsh, Wl, Af16, Btw, u);
        (void)hipFuncSetAttribute((const void*)k_gemm_256,
                                  hipFuncAttributeMaxDynamicSharedMemorySize, 131072);
        k_gemm_256<<<2048, 512, 131072, stream>>>(Af16, Btw, bik);
        k_scan_t<<<256, 128, 0, stream>>>(bik, u, out);
    } else if (ws_size >= bik_bytes + (2u << 20)) {
        // ---- fp32 big path (old layout) ----
        __half* bik = (__half*)ws;
        float* u = (float*)(ws + bik_bytes);

        k_usum<<<6400, 256, 0, stream>>>(Wl, u);
        dim3 g(64, 256);
        k_gemm<<<g, 256, 0, stream>>>(tensor, Wsh, bik, 0, 512);
        k_scan<<<512, 256, 0, stream>>>(bik, u, out);
    } else {
        // ---- per-t fallback ----
        __half* bikt = (__half*)ws;
        float* u = (float*)(ws + (size_t)(4 << 20));
        float* v0 = (float*)(ws + (size_t)(4 << 20) + (64 << 10));
        float* v1 = v0 + 32768;

        k_usum<<<6400, 256, 0, stream>>>(Wl, u);
        for (int t = 0; t < 64; ++t) {
            dim3 g(64, 4);
            k_gemm<<<g, 256, 0, stream>>>(tensor, Wsh, bikt, t * 512, 32768);
            float* vin = (t & 1) ? v0 : v1;
            float* vout = (t & 1) ? v1 : v0;
            k_update<<<128, 256, 0, stream>>>(bikt, (t == 0) ? v0 : vin, vout, t == 0);
        }
        k_final<<<200, 256, 0, stream>>>(u, v1, out);
    }
}